// Round 5
// baseline (249.099 us; speedup 1.0000x reference)
//
#include <hip/hip_runtime.h>

// Muskingum-Cunge routing, MI355X — single outlet chain (out = Q[15, 2047]).
// 16-lane systolic pipeline, lane = level, DPP row_shr:1 handoff of (numc, rd).
//
// Trans-minimized step (1 trans vs round-2's 4):
//   x    = max(Inew + Qold, 2*QMIN)            (x = 2*Qref)
//   y    = x^-0.2  via bit-trick seed + 2 Newton (y <- y*(1.2 - 0.2*x*y^5))
//   Kh   = A2*y ;  Ku = (B2*sqrt(x))*y^2        (x^0.1 = sqrt(x)*y^2, sqrt parallel)
//   Kmin = min(Ku, Kh) ; denom = (HDT+Kh)+Kmin
//   rd   = 1/denom via warm-start Newton x2 from previous rd (HDT-dominated)
//   num  = Kh*P1 + Kmin*P2 + HDT*sI ; numc = max(num,0) ; Qnew = numc*rd
// Pre-activation (all-zero state, lat=0) is an exact fixed point: numc=0 -> Q=0.

#define T_STEPS 730
#define NROWS   (T_STEPS + 14)   // 4 leading zero rows + 730 data + 10 zero pad
#define HDT     10800.0f         // 0.5 * (86400/4)
#define QMIN2   2e-3f            // 2 * Q_MIN  (floor on x = 2*Qref)
#define MAGICF  1.2779704e9f     // K = 1.2 * (2^23 * 126.957)  for y0 = x^-0.2

__device__ __forceinline__ float dpp0(float x) {
    // lane i <- lane i-1 in rows of 16; lanes 0/16/32/48 get 0 (bound_ctrl)
    return __int_as_float(__builtin_amdgcn_mov_dpp(__float_as_int(x), 0x111, 0xF, 0xF, true));
}

__global__ __launch_bounds__(1024, 1)
void mc_route(const float* __restrict__ inflow,
              const float* __restrict__ log_n,
              const float* __restrict__ dxs,
              const float* __restrict__ slopes,
              float* __restrict__ out)
{
    __shared__ float lat_s[NROWS * 16];

    const int tid = threadIdx.x;
    for (int i = tid; i < NROWS * 16; i += 1024) {
        int t = (i >> 4) - 4;
        float v = 0.0f;
        if ((unsigned)t < (unsigned)T_STEPS)
            v = inflow[t * 32768 + (i & 15) * 2048 + 2047];
        lat_s[i] = v;
    }
    __syncthreads();
    if (tid >= 64) return;       // wave 0 runs the pipeline

    const int lane = tid;
    const int lvl  = lane < 15 ? lane : 15;   // lanes 16..63 ride along (benign)
    const int g    = lvl * 2048 + 2047;

    const float nman  = expf(log_n[g]);
    const float S     = slopes[g];
    const float dx    = dxs[g];
    const float invA2 = 1.4362848f * nman / __builtin_amdgcn_sqrtf(S);
    // Kh = A*Qref^-0.2 = A2*x^-0.2 ; Ku = B*Qref^0.1 = B2*x^0.1  (x = 2*Qref)
    const float A2 = 0.5f * dx * invA2 * 1.1486984f;             // A * 2^0.2
    const float B2 = 0.5f * invA2 * invA2 / (7.2f * S) * 0.93303299f; // B * 2^-0.1

    // exact rd fixed point at x = QMIN2 (pre-activation state)
    const float y0t  = exp2f(-0.2f * log2f(QMIN2));
    const float Kh0  = A2 * y0t;
    const float Ku0  = B2 * sqrtf(QMIN2) * y0t * y0t;
    const float rd_init = 1.0f / ((HDT + Kh0) + fminf(Ku0, Kh0));

    // rotating LDS pointers (buffer j refilled at steps k===j mod 4, for k+4)
    const float* p0 = lat_s + (5 + ((0 - lvl) >> 2)) * 16 + lvl;
    const float* p1 = lat_s + (5 + ((1 - lvl) >> 2)) * 16 + lvl;
    const float* p2 = lat_s + (5 + ((2 - lvl) >> 2)) * 16 + lvl;
    const float* p3 = lat_s + (5 + ((3 - lvl) >> 2)) * 16 + lvl;

    float b0 = lat_s[(4 + ((0 - lvl) >> 2)) * 16 + lvl];
    float b1 = lat_s[(4 + ((1 - lvl) >> 2)) * 16 + lvl];
    float b2 = lat_s[(4 + ((2 - lvl) >> 2)) * 16 + lvl];
    float b3 = lat_s[(4 + ((3 - lvl) >> 2)) * 16 + lvl];

    // State: numc (clamped numerator), rd (1/denom), Qv = numc*rd, Iold.
    float numc = 0.0f, rd = rd_init, Qv = 0.0f, Iold = 0.0f;

#define STEP(BUF, LD_EXPR, STCODE) do {                                   \
    const float lat  = BUF;                                               \
    BUF = (LD_EXPR);                     /* prefetch for k+4 */           \
    const float up_n = dpp0(numc);                                        \
    const float up_r = dpp0(rd);                                          \
    const float Inew = fmaf(up_n, up_r, lat);   /* upQ + lat */           \
    const float x    = fmaxf(fmaf(numc, rd, Inew), QMIN2); /* 2*Qref */   \
    /* y = x^-0.2 : bit-trick seed + 2 Newtons */                         \
    const float fi = (float)__float_as_uint(x);                           \
    const float gf = fmaf(-0.2f, fi, MAGICF);                             \
    const float cx = -0.2f * x;                                           \
    const float sq = __builtin_amdgcn_sqrtf(x);     /* parallel trans */  \
    const float Bsx = B2 * sq;                                            \
    float y  = __uint_as_float((unsigned)gf);                             \
    float y2 = y * y, y4 = y2 * y2, y5 = y4 * y;                          \
    y  = y * fmaf(cx, y5, 1.2f);                                          \
    y2 = y * y; y4 = y2 * y2; y5 = y4 * y;                                \
    y  = y * fmaf(cx, y5, 1.2f);                                          \
    const float Kh  = A2 * y;                                             \
    const float y2b = y * y;                                              \
    const float Ku  = Bsx * y2b;                                          \
    const float Kmn = fminf(Ku, Kh);                                      \
    const float den = (HDT + Kh) + Kmn;                                   \
    /* value-form linear terms (off the y-chain) */                       \
    const float Siq = Iold + Qv;                                          \
    const float Dif = Iold - Qv;                                          \
    const float P1  = Siq - Inew;                                         \
    const float P2  = Inew - Dif;                                         \
    const float hsI = fmaf(HDT, Inew, HDT * Dif);                         \
    const float n1  = fmaf(Kh, P1, hsI);                                  \
    const float n2  = fmaf(Kmn, P2, n1);                                  \
    const float nc  = fmaxf(n2, 0.0f);                                    \
    /* rd' = 1/den via Newton x2, seeded by previous rd */                \
    float tt = den * rd;                                                  \
    float hh = 2.0f - tt;                                                 \
    float r1 = rd * hh;                                                   \
    tt = den * r1; hh = 2.0f - tt; r1 = r1 * hh;                          \
    numc = nc; rd = r1;                                                   \
    const float Qnew = numc * rd;        /* off-chain: store/state only */ \
    STCODE                                                                \
    Qv = Qnew; Iold = Inew;                                               \
} while (0);

    // ---- Prologue: k = 0..15 (no valid stores; first store at k=18) ----
    STEP(b0, p0[0],  {}) STEP(b1, p1[0],  {}) STEP(b2, p2[0],  {}) STEP(b3, p3[0],  {})
    STEP(b0, p0[16], {}) STEP(b1, p1[16], {}) STEP(b2, p2[16], {}) STEP(b3, p3[16], {})
    STEP(b0, p0[32], {}) STEP(b1, p1[32], {}) STEP(b2, p2[32], {}) STEP(b3, p3[32], {})
    STEP(b0, p0[48], {}) STEP(b1, p1[48], {}) STEP(b2, p2[48], {}) STEP(b3, p3[48], {})
    p0 += 64; p1 += 64; p2 += 64; p3 += 64;

    // ---- Main: 182 blocks x 16 steps (k = 16..2927); store at k%4==2 ----
    float* outp = out;
    #pragma unroll 1
    for (int blk = 0; blk < 182; ++blk) {
        float4 st;
        STEP(b0, p0[0],  {}) STEP(b1, p1[0],  {}) STEP(b2, p2[0],  st.x = Qnew;) STEP(b3, p3[0],  {})
        STEP(b0, p0[16], {}) STEP(b1, p1[16], {}) STEP(b2, p2[16], st.y = Qnew;) STEP(b3, p3[16], {})
        STEP(b0, p0[32], {}) STEP(b1, p1[32], {}) STEP(b2, p2[32], st.z = Qnew;) STEP(b3, p3[32], {})
        STEP(b0, p0[48], {}) STEP(b1, p1[48], {}) STEP(b2, p2[48], st.w = Qnew;) STEP(b3, p3[48], {})
        if (lane == 15) *reinterpret_cast<float4*>(outp) = st;
        outp += 4;
        p0 += 64; p1 += 64; p2 += 64; p3 += 64;
    }

    // ---- Epilogue: k = 2928..2935; stores idx 728 (k=2930), 729 (k=2934) ----
    {
        float2 st2;
        STEP(b0, p0[0],  {}) STEP(b1, p1[0],  {}) STEP(b2, p2[0],  st2.x = Qnew;) STEP(b3, p3[0],  {})
        STEP(b0, p0[16], {}) STEP(b1, p1[16], {}) STEP(b2, p2[16], st2.y = Qnew;) STEP(b3, p3[16], {})
        if (lane == 15) *reinterpret_cast<float2*>(out + 728) = st2;
    }
#undef STEP
}

extern "C" void kernel_launch(void* const* d_in, const int* in_sizes, int n_in,
                              void* d_out, int out_size, void* d_ws, size_t ws_size,
                              hipStream_t stream) {
    const float* inflow = (const float*)d_in[0];
    const float* log_n  = (const float*)d_in[1];
    const float* dxs    = (const float*)d_in[2];
    const float* slopes = (const float*)d_in[3];
    float* out = (float*)d_out;
    mc_route<<<1, 1024, 0, stream>>>(inflow, log_n, dxs, slopes, out);
}

// Round 6
// 165.101 us; speedup vs baseline: 1.5088x; 1.5088x over previous
//
#include <hip/hip_runtime.h>

// Muskingum-Cunge routing, MI355X — single outlet chain (out = Q[15, 2047]).
// 16-lane systolic pipeline (lane = level), DPP row_shr:1 handoff.
//
// Round-6: coefficient pipelining. Exact rewrite of the update:
//   num = a1*Inew + Kh*Siq + a3*Dif,  a1 = den - 2*Kh, a3 = HDT - Kmn,
//   den = HDT + Kh + Kmn,  Qnew = max(num,0) * (1/den)
// Coefficients {Kh,Kmn,rd,a1,a3} are computed from the Qref proxy x~ =
// Inew+Qnew recorded THREE substeps earlier, software-pipelined:
//   stage1: lg = log2(max(x~,QMIN2))   (slot k-3)
//   stage2: Kh = exp2(-0.2*lg+lKh1), Kmn = exp2(min(...))   (slot k-2)
//   stage3: den, rd = rcp(den), a1, a3                      (slot k-1)
// -> the temporal recurrence has NO transcendentals: dpp->add->fma->max->mul.
// First 32 steps use the exact (r2-form) update to cover activation
// transients; zero state is an exact fixed point under any coefficients.

#define T_STEPS 730
#define NROWS   (T_STEPS + 14)   // 4 leading zero rows + 730 data + 10 zero pad
#define HDT     10800.0f         // 0.5 * (86400/4)
#define QMIN2   2e-3f            // 2 * Q_MIN (x = 2*Qref)

__device__ __forceinline__ float dpp0(float x) {
    // lane i <- lane i-1 in rows of 16; lanes 0/16/32/48 get 0 (bound_ctrl)
    return __int_as_float(__builtin_amdgcn_mov_dpp(__float_as_int(x), 0x111, 0xF, 0xF, true));
}

__global__ __launch_bounds__(1024, 1)
void mc_route(const float* __restrict__ inflow,
              const float* __restrict__ log_n,
              const float* __restrict__ dxs,
              const float* __restrict__ slopes,
              float* __restrict__ out)
{
    __shared__ float lat_s[NROWS * 16];

    const int tid = threadIdx.x;
    for (int i = tid; i < NROWS * 16; i += 1024) {
        int t = (i >> 4) - 4;
        float v = 0.0f;
        if ((unsigned)t < (unsigned)T_STEPS)
            v = inflow[t * 32768 + (i & 15) * 2048 + 2047];
        lat_s[i] = v;
    }
    __syncthreads();
    if (tid >= 64) return;       // wave 0 runs the pipeline

    const int lane = tid;
    const int lvl  = lane < 15 ? lane : 15;   // lanes 16..63 ride along (benign)
    const int g    = lvl * 2048 + 2047;

    const float nman  = expf(log_n[g]);
    const float S     = slopes[g];
    const float dx    = dxs[g];
    const float invA2 = 1.4362848f * nman / __builtin_amdgcn_sqrtf(S);
    const float A     = 0.5f * dx * invA2;                 // Kh = A*Qref^-0.2
    const float B     = 0.5f * invA2 * invA2 / (7.2f * S); // Ku = B*Qref^0.1
    const float lKh1  = log2f(A) + 0.2f;   // x = 2*Qref folded in
    const float lKu1  = log2f(B) - 0.1f;

    // rotating LDS pointers (buffer j refilled at steps k===j mod 4, for k+4)
    const float* p0 = lat_s + (5 + ((0 - lvl) >> 2)) * 16 + lvl;
    const float* p1 = lat_s + (5 + ((1 - lvl) >> 2)) * 16 + lvl;
    const float* p2 = lat_s + (5 + ((2 - lvl) >> 2)) * 16 + lvl;
    const float* p3 = lat_s + (5 + ((3 - lvl) >> 2)) * 16 + lvl;

    float b0 = lat_s[(4 + ((0 - lvl) >> 2)) * 16 + lvl];
    float b1 = lat_s[(4 + ((1 - lvl) >> 2)) * 16 + lvl];
    float b2 = lat_s[(4 + ((2 - lvl) >> 2)) * 16 + lvl];
    float b3 = lat_s[(4 + ((3 - lvl) >> 2)) * 16 + lvl];

    float Qnew = 0.0f, Iold = 0.0f;
    float xm1 = QMIN2, xm2 = QMIN2, xm3 = QMIN2;   // x~ history (k-1,k-2,k-3)

// ---------- exact step (reference algebra, r2-validated) ----------
#define STEPX(BUF, LD, ST) do {                                           \
    const float lat = BUF; BUF = (LD);                                    \
    const float up  = dpp0(Qnew);                                         \
    const float Inew = up + lat;                                          \
    const float x   = fmaxf(Inew + Qnew, QMIN2);                          \
    const float lg  = __builtin_amdgcn_logf(x);                           \
    const float tKh = fmaf(-0.2f, lg, lKh1);                              \
    const float tKu = fmaf( 0.1f, lg, lKu1);                              \
    const float tmn = fminf(tKu, tKh);                                    \
    const float Kh  = __builtin_amdgcn_exp2f(tKh);                        \
    const float Km  = __builtin_amdgcn_exp2f(tmn);                        \
    const float den = (HDT + Kh) + Km;                                    \
    const float rd  = __builtin_amdgcn_rcpf(den);                         \
    const float Siq = Iold + Qnew;                                        \
    const float Dif = Iold - Qnew;                                        \
    const float a1  = fmaf(-2.0f, Kh, den);   /* HDT+Km-Kh */             \
    const float a3  = HDT - Km;                                           \
    const float num = fmaf(a1, Inew, fmaf(Kh, Siq, a3 * Dif));            \
    const float Qn2 = fmaxf(num, 0.0f) * rd;                              \
    ST                                                                    \
    xm3 = xm2; xm2 = xm1; xm1 = Inew + Qn2;                               \
    Iold = Inew; Qnew = Qn2;                                              \
} while (0);

// ---------- pipelined step: consume set C; build stages for +1,+2,+3 ----------
#define SLOT(BUF, LD, ST, KhC, a1C, a3C, rdC, KhN, KmN, rdN, a1N, a3N, lgP, KhP, KmP, lgQ) do { \
    const float lat = BUF; BUF = (LD);                                    \
    const float up  = dpp0(Qnew);                                         \
    const float Inew = up + lat;                                          \
    const float Siq = Iold + Qnew;                                        \
    const float Dif = Iold - Qnew;                                        \
    const float num = fmaf(a1C, Inew, fmaf(KhC, Siq, a3C * Dif));         \
    const float Qn2 = fmaxf(num, 0.0f) * rdC;                             \
    ST                                                                    \
    /* stage3 for set+1 */                                                \
    const float denN = (HDT + KhN) + KmN;                                 \
    rdN = __builtin_amdgcn_rcpf(denN);                                    \
    a1N = fmaf(-2.0f, KhN, denN);                                         \
    a3N = HDT - KmN;                                                      \
    /* stage2 for set+2 */                                                \
    const float tKh = fmaf(-0.2f, lgP, lKh1);                             \
    const float tKu = fmaf( 0.1f, lgP, lKu1);                             \
    const float tmn = fminf(tKu, tKh);                                    \
    KhP = __builtin_amdgcn_exp2f(tKh);                                    \
    KmP = __builtin_amdgcn_exp2f(tmn);                                    \
    /* stage1 for set+3 */                                                \
    lgQ = __builtin_amdgcn_logf(fmaxf(Inew + Qn2, QMIN2));                \
    Iold = Inew; Qnew = Qn2;                                              \
} while (0);

    // ---- Exact prologue: k = 0..31 (covers all activation transients) ----
    STEPX(b0, p0[0],  {}) STEPX(b1, p1[0],  {}) STEPX(b2, p2[0],  {}) STEPX(b3, p3[0],  {})
    STEPX(b0, p0[16], {}) STEPX(b1, p1[16], {}) STEPX(b2, p2[16], {}) STEPX(b3, p3[16], {})
    STEPX(b0, p0[32], {}) STEPX(b1, p1[32], {}) STEPX(b2, p2[32], {}) STEPX(b3, p3[32], {})
    STEPX(b0, p0[48], {}) STEPX(b1, p1[48], {}) STEPX(b2, p2[48], {}) STEPX(b3, p3[48], {})
    p0 += 64; p1 += 64; p2 += 64; p3 += 64;
    {
        float4 st;   // outputs t = 0..3 at k = 18,22,26,30
        STEPX(b0, p0[0],  {}) STEPX(b1, p1[0],  {}) STEPX(b2, p2[0],  st.x = Qn2;) STEPX(b3, p3[0],  {})
        STEPX(b0, p0[16], {}) STEPX(b1, p1[16], {}) STEPX(b2, p2[16], st.y = Qn2;) STEPX(b3, p3[16], {})
        STEPX(b0, p0[32], {}) STEPX(b1, p1[32], {}) STEPX(b2, p2[32], st.z = Qn2;) STEPX(b3, p3[32], {})
        STEPX(b0, p0[48], {}) STEPX(b1, p1[48], {}) STEPX(b2, p2[48], st.w = Qn2;) STEPX(b3, p3[48], {})
        if (lane == 15) *reinterpret_cast<float4*>(out) = st;
    }
    p0 += 64; p1 += 64; p2 += 64; p3 += 64;

    // ---- Seed the coefficient pipeline from exact history ----
    float lg0, lg1, lg2, lg3 = 0.0f;
    float Kh0, Km0, rd0, a10, a30;
    float Kh1, Km1, rd1 = 0.0f, a11 = 0.0f, a31 = 0.0f;
    float Kh2 = 0.0f, Km2 = 0.0f, rd2 = 0.0f, a12 = 0.0f, a32 = 0.0f;
    float Kh3 = 0.0f, Km3 = 0.0f, rd3 = 0.0f, a13 = 0.0f, a33 = 0.0f;
    {   // set0 (consumed k=32): full, from x~(k=29)
        lg0 = __builtin_amdgcn_logf(fmaxf(xm3, QMIN2));
        const float tKh = fmaf(-0.2f, lg0, lKh1);
        const float tKu = fmaf( 0.1f, lg0, lKu1);
        Kh0 = __builtin_amdgcn_exp2f(tKh);
        Km0 = __builtin_amdgcn_exp2f(fminf(tKu, tKh));
        const float den = (HDT + Kh0) + Km0;
        rd0 = __builtin_amdgcn_rcpf(den);
        a10 = fmaf(-2.0f, Kh0, den);
        a30 = HDT - Km0;
    }
    {   // set1 (k=33): stages 1-2, from x~(k=30); stage3 runs in slot k=32
        lg1 = __builtin_amdgcn_logf(fmaxf(xm2, QMIN2));
        const float tKh = fmaf(-0.2f, lg1, lKh1);
        const float tKu = fmaf( 0.1f, lg1, lKu1);
        Kh1 = __builtin_amdgcn_exp2f(tKh);
        Km1 = __builtin_amdgcn_exp2f(fminf(tKu, tKh));
    }
    // set2 (k=34): stage 1 only, from x~(k=31)
    lg2 = __builtin_amdgcn_logf(fmaxf(xm1, QMIN2));

    // ---- Main: 181 blocks x 16 steps (k = 32..2927); store at k%4==2 ----
    float* outp = out + 4;
    #pragma unroll 1
    for (int blk = 0; blk < 181; ++blk) {
        float4 st;
        SLOT(b0, p0[0],  {},            Kh0,a10,a30,rd0, Kh1,Km1,rd1,a11,a31, lg2,Kh2,Km2, lg3)
        SLOT(b1, p1[0],  {},            Kh1,a11,a31,rd1, Kh2,Km2,rd2,a12,a32, lg3,Kh3,Km3, lg0)
        SLOT(b2, p2[0],  st.x = Qn2;,   Kh2,a12,a32,rd2, Kh3,Km3,rd3,a13,a33, lg0,Kh0,Km0, lg1)
        SLOT(b3, p3[0],  {},            Kh3,a13,a33,rd3, Kh0,Km0,rd0,a10,a30, lg1,Kh1,Km1, lg2)
        SLOT(b0, p0[16], {},            Kh0,a10,a30,rd0, Kh1,Km1,rd1,a11,a31, lg2,Kh2,Km2, lg3)
        SLOT(b1, p1[16], {},            Kh1,a11,a31,rd1, Kh2,Km2,rd2,a12,a32, lg3,Kh3,Km3, lg0)
        SLOT(b2, p2[16], st.y = Qn2;,   Kh2,a12,a32,rd2, Kh3,Km3,rd3,a13,a33, lg0,Kh0,Km0, lg1)
        SLOT(b3, p3[16], {},            Kh3,a13,a33,rd3, Kh0,Km0,rd0,a10,a30, lg1,Kh1,Km1, lg2)
        SLOT(b0, p0[32], {},            Kh0,a10,a30,rd0, Kh1,Km1,rd1,a11,a31, lg2,Kh2,Km2, lg3)
        SLOT(b1, p1[32], {},            Kh1,a11,a31,rd1, Kh2,Km2,rd2,a12,a32, lg3,Kh3,Km3, lg0)
        SLOT(b2, p2[32], st.z = Qn2;,   Kh2,a12,a32,rd2, Kh3,Km3,rd3,a13,a33, lg0,Kh0,Km0, lg1)
        SLOT(b3, p3[32], {},            Kh3,a13,a33,rd3, Kh0,Km0,rd0,a10,a30, lg1,Kh1,Km1, lg2)
        SLOT(b0, p0[48], {},            Kh0,a10,a30,rd0, Kh1,Km1,rd1,a11,a31, lg2,Kh2,Km2, lg3)
        SLOT(b1, p1[48], {},            Kh1,a11,a31,rd1, Kh2,Km2,rd2,a12,a32, lg3,Kh3,Km3, lg0)
        SLOT(b2, p2[48], st.w = Qn2;,   Kh2,a12,a32,rd2, Kh3,Km3,rd3,a13,a33, lg0,Kh0,Km0, lg1)
        SLOT(b3, p3[48], {},            Kh3,a13,a33,rd3, Kh0,Km0,rd0,a10,a30, lg1,Kh1,Km1, lg2)
        if (lane == 15) *reinterpret_cast<float4*>(outp) = st;
        outp += 4;
        p0 += 64; p1 += 64; p2 += 64; p3 += 64;
    }

    // ---- Epilogue: k = 2928..2935; stores t=728 (k=2930), t=729 (k=2934) ----
    {
        float2 st2;
        SLOT(b0, p0[0],  {},            Kh0,a10,a30,rd0, Kh1,Km1,rd1,a11,a31, lg2,Kh2,Km2, lg3)
        SLOT(b1, p1[0],  {},            Kh1,a11,a31,rd1, Kh2,Km2,rd2,a12,a32, lg3,Kh3,Km3, lg0)
        SLOT(b2, p2[0],  st2.x = Qn2;,  Kh2,a12,a32,rd2, Kh3,Km3,rd3,a13,a33, lg0,Kh0,Km0, lg1)
        SLOT(b3, p3[0],  {},            Kh3,a13,a33,rd3, Kh0,Km0,rd0,a10,a30, lg1,Kh1,Km1, lg2)
        SLOT(b0, p0[16], {},            Kh0,a10,a30,rd0, Kh1,Km1,rd1,a11,a31, lg2,Kh2,Km2, lg3)
        SLOT(b1, p1[16], {},            Kh1,a11,a31,rd1, Kh2,Km2,rd2,a12,a32, lg3,Kh3,Km3, lg0)
        SLOT(b2, p2[16], st2.y = Qn2;,  Kh2,a12,a32,rd2, Kh3,Km3,rd3,a13,a33, lg0,Kh0,Km0, lg1)
        SLOT(b3, p3[16], {},            Kh3,a13,a33,rd3, Kh0,Km0,rd0,a10,a30, lg1,Kh1,Km1, lg2)
        if (lane == 15) *reinterpret_cast<float2*>(out + 728) = st2;
    }
#undef SLOT
#undef STEPX
}

extern "C" void kernel_launch(void* const* d_in, const int* in_sizes, int n_in,
                              void* d_out, int out_size, void* d_ws, size_t ws_size,
                              hipStream_t stream) {
    const float* inflow = (const float*)d_in[0];
    const float* log_n  = (const float*)d_in[1];
    const float* dxs    = (const float*)d_in[2];
    const float* slopes = (const float*)d_in[3];
    float* out = (float*)d_out;
    mc_route<<<1, 1024, 0, stream>>>(inflow, log_n, dxs, slopes, out);
}